// Round 13
// baseline (82.030 us; speedup 1.0000x reference)
//
#include <hip/hip_runtime.h>
#include <hip/hip_bf16.h>

typedef float  f32x4  __attribute__((ext_vector_type(4)));
typedef short  short8 __attribute__((ext_vector_type(8)));

#define BM 64
#define RS 1600               // LDS row stride: 100 k-pairs * 16 B

static __device__ __forceinline__ unsigned short f2bf(float f) {
    unsigned int u = __float_as_uint(f);
    unsigned int r = (u + 0x7fffu + ((u >> 16) & 1u)) >> 16;   // RNE
    return (unsigned short)r;
}
static __device__ __forceinline__ float bf2f(unsigned short h) {
    return __uint_as_float(((unsigned int)h) << 16);
}
static __device__ __forceinline__ uint2 pack4(f32x4 v) {
    __hip_bfloat162 p0 = __float22bfloat162_rn(make_float2(v[0], v[1]));
    __hip_bfloat162 p1 = __float22bfloat162_rn(make_float2(v[2], v[3]));
    uint2 r;
    r.x = *reinterpret_cast<unsigned int*>(&p0);
    r.y = *reinterpret_cast<unsigned int*>(&p1);
    return r;
}

// W_eff = fc1_w o ConvMatrix, layout [kt(25)][kc(4)][col(128)][8] bf16
// (elem idx = kt*4096 + kc*1024 + col*8 + e, p = kt*32 + kc*8 + e).
// Zero past p=783. fc2 bf16 at ws[102400..103679].
__global__ __launch_bounds__(256) void weff_prep(
    const float* __restrict__ fc1_w,    // [128][676]
    const float* __restrict__ conv_w,   // [3][3]
    const float* __restrict__ fc2_w,    // [10][128]
    unsigned short* __restrict__ ws)
{
    int idx = blockIdx.x * 256 + threadIdx.x;   // o*800 + p
    if (idx >= 128 * 800) return;
    if (idx < 1280) ws[102400 + idx] = f2bf(fc2_w[idx]);
    int o = idx / 800, p = idx - o * 800;
    float s = 0.f;
    if (p < 784) {
        int y = p / 28, xx = p - y * 28;
        #pragma unroll
        for (int dr = 0; dr < 3; ++dr) {
            int r = y - dr;
            if (r < 0 || r > 25) continue;
            #pragma unroll
            for (int dc = 0; dc < 3; ++dc) {
                int c = xx - dc;
                if (c < 0 || c > 25) continue;
                s += fc1_w[o * 676 + r * 26 + c] * conv_w[dr * 3 + dc];
            }
        }
    }
    ws[(p >> 5) * 4096 + ((p >> 3) & 3) * 1024 + o * 8 + (p & 7)] = f2bf(s);
}

// Fused: H = relu(X @ Weff^T + b1); out = H @ fc2^T + b2
// PHASE-SPLIT: phase 1 streams the block's 200 KB X region perfectly
// sequentially (flat P = tid + 512*s; row = P/98, pair = P%98 since
// 98 pairs * 8 floats = 784) -> bf16 -> whole A-tile in LDS (100 KB).
// Phase 2: K-loop from LDS + B 2-deep reg prefetch from L1/L2. No
// staging, no inline asm, 3 __syncthreads total. 1 block/CU.
__global__ __launch_bounds__(512, 2) void fused_fwd(
    const float* __restrict__ x,              // [B][784]
    const unsigned short* __restrict__ weff,  // [25][4][128][8] bf16 (+fc2wb)
    const float* __restrict__ fc1_b,          // [128]
    const float* __restrict__ fc2_b,          // [10]
    float* __restrict__ out,                  // [B][10]
    int B)
{
    __shared__ __align__(16) char pool[64 * RS];   // 102400 B; Hs overlays

    const int tid  = threadIdx.x;
    const int lane = tid & 63;
    const int wid  = tid >> 6;                // 0..7
    const int wr   = wid >> 1;                // 0..3: 16-row band
    const int wc   = wid & 1;                 // 0..1: 64-col half
    const int r16  = lane & 15;
    const int kc   = lane >> 4;               // 0..3
    const int m0   = blockIdx.x * BM;
    const unsigned short* fc2wb = weff + 102400;

    // ================= phase 1: sequential X stream -> LDS =================
    const float* xblk = x + (size_t)m0 * 784;   // block-exclusive 200 KB

    f32x4 av[8][2];
#define LD_P(s_) do {                                                         \
        const float* p_ = xblk + ((size_t)tid + 512 * (s_)) * 8;              \
        av[(s_) & 7][0] = *reinterpret_cast<const f32x4*>(p_);                \
        av[(s_) & 7][1] = *reinterpret_cast<const f32x4*>(p_ + 4);            \
    } while (0)
#define WR_P(s_) do {                                                         \
        int P_ = tid + 512 * (s_);                                            \
        int row_ = P_ / 98, pr_ = P_ - row_ * 98;                             \
        uint2 q0_ = pack4(av[(s_) & 7][0]);                                   \
        uint2 q1_ = pack4(av[(s_) & 7][1]);                                   \
        uint4 q_; q_.x = q0_.x; q_.y = q0_.y; q_.z = q1_.x; q_.w = q1_.y;     \
        *reinterpret_cast<uint4*>(pool + row_ * RS + pr_ * 16) = q_;          \
    } while (0)

    LD_P(0); LD_P(1); LD_P(2); LD_P(3);        // batch 0 in flight
    LD_P(4); LD_P(5); LD_P(6); LD_P(7);        // batch 1 in flight
    WR_P(0); WR_P(1); WR_P(2); WR_P(3);
    LD_P(8); LD_P(9); LD_P(10); LD_P(11);      // batch 2 in flight
    WR_P(4); WR_P(5); WR_P(6); WR_P(7);

    f32x4 tv0 = (f32x4)(0.f), tv1 = (f32x4)(0.f);
    if (tid < 128) {                           // tail: P = 6144..6271
        const float* p_ = xblk + ((size_t)6144 + tid) * 8;
        tv0 = *reinterpret_cast<const f32x4*>(p_);
        tv1 = *reinterpret_cast<const f32x4*>(p_ + 4);
    }
    WR_P(8); WR_P(9); WR_P(10); WR_P(11);
    if (tid < 128) {
        int P_ = 6144 + tid;
        int row_ = P_ / 98, pr_ = P_ - row_ * 98;
        uint2 q0_ = pack4(tv0), q1_ = pack4(tv1);
        uint4 q_; q_.x = q0_.x; q_.y = q0_.y; q_.z = q1_.x; q_.w = q1_.y;
        *reinterpret_cast<uint4*>(pool + row_ * RS + pr_ * 16) = q_;
        // zero-fill k-pairs 98,99 (k=784..799) so MFMA sees no garbage
        int zr = tid >> 1, zp = 98 + (tid & 1);
        uint4 z_; z_.x = 0; z_.y = 0; z_.z = 0; z_.w = 0;
        *reinterpret_cast<uint4*>(pool + zr * RS + zp * 16) = z_;
    }
#undef LD_P
#undef WR_P
    __syncthreads();

    // ================= phase 2: K-loop (LDS A + L2 B), no barriers =========
    const char* pa = pool + (wr * 16 + r16) * RS + kc * 16;   // + kt*64
    const unsigned short* wb = weff + kc * 1024 + (wc * 64 + r16) * 8;

    short8 breg[2][4];
#define LOADB(set_, kt_) do {                                                 \
        const unsigned short* p_ = wb + (size_t)(kt_) * 4096;                 \
        breg[set_][0] = *reinterpret_cast<const short8*>(p_);                 \
        breg[set_][1] = *reinterpret_cast<const short8*>(p_ + 128);           \
        breg[set_][2] = *reinterpret_cast<const short8*>(p_ + 256);           \
        breg[set_][3] = *reinterpret_cast<const short8*>(p_ + 384);           \
    } while (0)

    f32x4 acc[4];
    #pragma unroll
    for (int j = 0; j < 4; ++j) acc[j] = (f32x4)(0.f);

    LOADB(0, 0); LOADB(1, 1);

    #pragma unroll
    for (int kt = 0; kt < 25; ++kt) {
        short8 a  = *reinterpret_cast<const short8*>(pa + kt * 64);
        short8 b0 = breg[kt & 1][0], b1 = breg[kt & 1][1];
        short8 b2 = breg[kt & 1][2], b3 = breg[kt & 1][3];
        int kn = kt + 2; if (kn > 24) kn = 24;     // dummy re-read at tail
        LOADB(kt & 1, kn);
        acc[0] = __builtin_amdgcn_mfma_f32_16x16x32_bf16(a, b0, acc[0], 0, 0, 0);
        acc[1] = __builtin_amdgcn_mfma_f32_16x16x32_bf16(a, b1, acc[1], 0, 0, 0);
        acc[2] = __builtin_amdgcn_mfma_f32_16x16x32_bf16(a, b2, acc[2], 0, 0, 0);
        acc[3] = __builtin_amdgcn_mfma_f32_16x16x32_bf16(a, b3, acc[3], 0, 0, 0);
    }
#undef LOADB

    __syncthreads();   // all waves done reading A-tile before Hs overlay

    // ---- epilogue: bias + ReLU -> Hs (bf16), overlays pool ----
    unsigned short (*Hs)[136] = (unsigned short (*)[136])pool;
    #pragma unroll
    for (int j = 0; j < 4; ++j) {
        int ncol = wc * 64 + j * 16 + r16;
        float bias = fc1_b[ncol];
        #pragma unroll
        for (int r = 0; r < 4; ++r) {
            int mrow = wr * 16 + kc * 4 + r;
            float h = acc[j][r] + bias;
            Hs[mrow][ncol] = f2bf(h > 0.f ? h : 0.f);
        }
    }
    __syncthreads();

    // ---- stage 2: out[64][10] = Hs @ fc2^T + b2 (fc2 bf16 from L1) ----
    #pragma unroll
    for (int it = 0; it < 2; ++it) {
        int idx = it * 512 + tid;              // 0..1023, valid < 640
        if (idx < BM * 10) {
            int row = idx / 10, j = idx - row * 10;
            if ((m0 + row) < B) {
                float sum = fc2_b[j];
                const unsigned short* wrow = fc2wb + j * 128;
                #pragma unroll
                for (int n8 = 0; n8 < 16; ++n8) {
                    short8 h = *reinterpret_cast<const short8*>(&Hs[row][n8 * 8]);
                    short8 w = *reinterpret_cast<const short8*>(wrow + n8 * 8);
                    #pragma unroll
                    for (int k2 = 0; k2 < 8; ++k2)
                        sum += bf2f(((unsigned short*)&h)[k2]) *
                               bf2f(((unsigned short*)&w)[k2]);
                }
                out[(size_t)(m0 + row) * 10 + j] = sum;
            }
        }
    }
}

extern "C" void kernel_launch(void* const* d_in, const int* in_sizes, int n_in,
                              void* d_out, int out_size, void* d_ws, size_t ws_size,
                              hipStream_t stream) {
    const float* x      = (const float*)d_in[0];
    const float* conv_w = (const float*)d_in[1];
    const float* fc1_w  = (const float*)d_in[2];
    const float* fc1_b  = (const float*)d_in[3];
    const float* fc2_w  = (const float*)d_in[4];
    const float* fc2_b  = (const float*)d_in[5];
    float* out = (float*)d_out;
    unsigned short* ws = (unsigned short*)d_ws;   // 103680 bf16 = 207360 B

    int B = in_sizes[0] / 784;

    weff_prep<<<(128 * 800 + 255) / 256, 256, 0, stream>>>(fc1_w, conv_w, fc2_w, ws);

    int nblk = (B + BM - 1) / BM;
    fused_fwd<<<nblk, 512, 0, stream>>>(x, ws, fc1_b, fc2_b, out, B);
}

// Round 14
// 74.908 us; speedup vs baseline: 1.0951x; 1.0951x over previous
//
#include <hip/hip_runtime.h>
#include <hip/hip_bf16.h>

typedef float  f32x4  __attribute__((ext_vector_type(4)));
typedef short  short8 __attribute__((ext_vector_type(8)));

#define BM  64
#define AB  24576             // one A buf: [64 rows][24 slots of 16B] (192 k bf16)
#define RSB 384               // row stride bytes in A buf

static __device__ __forceinline__ unsigned short f2bf(float f) {
    unsigned int u = __float_as_uint(f);
    unsigned int r = (u + 0x7fffu + ((u >> 16) & 1u)) >> 16;   // RNE
    return (unsigned short)r;
}
static __device__ __forceinline__ float bf2f(unsigned short h) {
    return __uint_as_float(((unsigned int)h) << 16);
}
static __device__ __forceinline__ uint2 pack4(f32x4 v) {
    __hip_bfloat162 p0 = __float22bfloat162_rn(make_float2(v[0], v[1]));
    __hip_bfloat162 p1 = __float22bfloat162_rn(make_float2(v[2], v[3]));
    uint2 r;
    r.x = *reinterpret_cast<unsigned int*>(&p0);
    r.y = *reinterpret_cast<unsigned int*>(&p1);
    return r;
}

// W_eff = fc1_w o ConvMatrix, layout [kt(25)][kc(4)][col(128)][8] bf16
// (elem idx = kt*4096 + kc*1024 + col*8 + e, p = kt*32 + kc*8 + e).
// Zero past p=783. fc2 bf16 at ws[102400..103679].
__global__ __launch_bounds__(256) void weff_prep(
    const float* __restrict__ fc1_w,    // [128][676]
    const float* __restrict__ conv_w,   // [3][3]
    const float* __restrict__ fc2_w,    // [10][128]
    unsigned short* __restrict__ ws)
{
    int idx = blockIdx.x * 256 + threadIdx.x;   // o*800 + p
    if (idx >= 128 * 800) return;
    if (idx < 1280) ws[102400 + idx] = f2bf(fc2_w[idx]);
    int o = idx / 800, p = idx - o * 800;
    float s = 0.f;
    if (p < 784) {
        int y = p / 28, xx = p - y * 28;
        #pragma unroll
        for (int dr = 0; dr < 3; ++dr) {
            int r = y - dr;
            if (r < 0 || r > 25) continue;
            #pragma unroll
            for (int dc = 0; dc < 3; ++dc) {
                int c = xx - dc;
                if (c < 0 || c > 25) continue;
                s += fc1_w[o * 676 + r * 26 + c] * conv_w[dr * 3 + dc];
            }
        }
    }
    ws[(p >> 5) * 4096 + ((p >> 3) & 3) * 1024 + o * 8 + (p & 7)] = f2bf(s);
}

// Fused: H = relu(X @ Weff^T + b1); out = H @ fc2^T + b2
// Chunked phase-split: K in 4 chunks of 192 (+32 tail). Per chunk the
// block streams 64 rows x 768B contiguous (reg-staged, cvt to bf16,
// swizzled LDS write), double-buffered 2x24KB -> 48KB LDS, 3 blocks/CU.
// Compute chunk c (6 steps: ds_read A + 2-deep reg B from L2 + 4 MFMA)
// overlaps global loads of chunk c+1. 8 barriers/block, no inline asm.
__global__ __launch_bounds__(512, 4) void fused_fwd(
    const float* __restrict__ x,              // [B][784]
    const unsigned short* __restrict__ weff,  // [25][4][128][8] bf16 (+fc2wb)
    const float* __restrict__ fc1_b,          // [128]
    const float* __restrict__ fc2_b,          // [10]
    float* __restrict__ out,                  // [B][10]
    int B)
{
    __shared__ __align__(16) char pool[2 * AB];   // 48 KB; Hs overlays after

    const int tid  = threadIdx.x;
    const int lane = tid & 63;
    const int wid  = tid >> 6;                // 0..7
    const int wr   = wid >> 1;                // 0..3: 16-row band
    const int wc   = wid & 1;                 // 0..1: 64-col half
    const int r16  = lane & 15;
    const int kc   = lane >> 4;               // 0..3
    const int m0   = blockIdx.x * BM;
    const unsigned short* fc2wb = weff + 102400;

    // ---- A staging geometry: thread t -> row t/8, 24 consecutive floats
    const int srow = tid >> 3;                // 0..63
    const int st8  = tid & 7;                 // 24-float sub-segment
    const int swr  = srow & 7;
    int grow = m0 + srow; if (grow >= B) grow = B - 1;
    const float* xr = x + (size_t)grow * 784;

    f32x4 sv[6];
#define LD_CH(c_) do {                                                        \
        const float* p_ = xr + (c_) * 192 + st8 * 24;                         \
        sv[0] = *reinterpret_cast<const f32x4*>(p_);                          \
        sv[1] = *reinterpret_cast<const f32x4*>(p_ + 4);                      \
        sv[2] = *reinterpret_cast<const f32x4*>(p_ + 8);                      \
        sv[3] = *reinterpret_cast<const f32x4*>(p_ + 12);                     \
        sv[4] = *reinterpret_cast<const f32x4*>(p_ + 16);                     \
        sv[5] = *reinterpret_cast<const f32x4*>(p_ + 20);                     \
    } while (0)

#define WR_CH(buf_) do {                                                     \
        char* bp_ = pool + (buf_) * AB + srow * RSB;                          \
        _Pragma("unroll")                                                     \
        for (int w_ = 0; w_ < 3; ++w_) {                                      \
            uint2 lo_ = pack4(sv[w_ * 2]);                                    \
            uint2 hi_ = pack4(sv[w_ * 2 + 1]);                                \
            uint4 q_; q_.x = lo_.x; q_.y = lo_.y; q_.z = hi_.x; q_.w = hi_.y; \
            int slot_ = (st8 * 3 + w_) ^ swr;                                 \
            *reinterpret_cast<uint4*>(bp_ + slot_ * 16) = q_;                 \
        }                                                                     \
    } while (0)

    // ---- B: 2-deep register prefetch, dense 16B/lane from L2 ----
    const unsigned short* wb = weff + kc * 1024 + (size_t)(wc * 64 + r16) * 8;
    short8 breg[2][4];
#define LOADB(set_, kt_) do {                                                 \
        const unsigned short* p_ = wb + (size_t)(kt_) * 4096;                 \
        breg[set_][0] = *reinterpret_cast<const short8*>(p_);                 \
        breg[set_][1] = *reinterpret_cast<const short8*>(p_ + 128);           \
        breg[set_][2] = *reinterpret_cast<const short8*>(p_ + 256);           \
        breg[set_][3] = *reinterpret_cast<const short8*>(p_ + 384);           \
    } while (0)

    // ---- A-frag read base: row = wr*16+r16, slot = (s*4+kc) ^ (r16&7)
    const int arow = wr * 16 + r16;
    const char* abase = pool + arow * RSB;
    const int asw = r16 & 7;

    f32x4 acc[4];
    #pragma unroll
    for (int j = 0; j < 4; ++j) acc[j] = (f32x4)(0.f);

    // ---- prologue ----
    LD_CH(0);
    WR_CH(0);                                  // compiler waits the 6 loads
    LOADB(0, 0); LOADB(1, 1);
    __syncthreads();

    f32x4 tv = (f32x4)(0.f);                   // tail chunk (k 768..799)

    #pragma unroll
    for (int c = 0; c < 4; ++c) {
        // issue next chunk's global loads (overlap with this chunk's compute)
        if (c < 3) {
            LD_CH(c + 1);
        } else {
            int tk = 768 + st8 * 4;
            if (tk <= 780) tv = *reinterpret_cast<const f32x4*>(xr + tk);
        }

        const char* bufp = (c & 1) ? (abase + AB) : abase;
        #pragma unroll
        for (int s = 0; s < 6; ++s) {
            const int step = c * 6 + s;
            short8 a = *reinterpret_cast<const short8*>(
                bufp + (((s * 4 + kc) ^ asw) * 16));
            short8 b0 = breg[step & 1][0], b1 = breg[step & 1][1];
            short8 b2 = breg[step & 1][2], b3 = breg[step & 1][3];
            int kn = step + 2; if (kn > 24) kn = 24;
            LOADB(step & 1, kn);
            acc[0] = __builtin_amdgcn_mfma_f32_16x16x32_bf16(a, b0, acc[0], 0, 0, 0);
            acc[1] = __builtin_amdgcn_mfma_f32_16x16x32_bf16(a, b1, acc[1], 0, 0, 0);
            acc[2] = __builtin_amdgcn_mfma_f32_16x16x32_bf16(a, b2, acc[2], 0, 0, 0);
            acc[3] = __builtin_amdgcn_mfma_f32_16x16x32_bf16(a, b3, acc[3], 0, 0, 0);
        }

        // write staged chunk into the other buffer
        if (c < 3) {
            WR_CH((c + 1) & 1);
        } else {
            // tail: 8 bf16 (16B slot shared by thread pairs) into buf 0
            uint2 q = pack4(tv);
            int slot = (st8 >> 1) ^ swr;
            *reinterpret_cast<uint2*>(pool + srow * RSB + slot * 16
                                      + (st8 & 1) * 8) = q;
        }
        __syncthreads();
    }

    // ---- tail step 24 (chunk 4, 1 step, buf 0, s=0) ----
    {
        short8 a = *reinterpret_cast<const short8*>(abase + ((kc ^ asw) * 16));
        acc[0] = __builtin_amdgcn_mfma_f32_16x16x32_bf16(a, breg[0][0], acc[0], 0, 0, 0);
        acc[1] = __builtin_amdgcn_mfma_f32_16x16x32_bf16(a, breg[0][1], acc[1], 0, 0, 0);
        acc[2] = __builtin_amdgcn_mfma_f32_16x16x32_bf16(a, breg[0][2], acc[2], 0, 0, 0);
        acc[3] = __builtin_amdgcn_mfma_f32_16x16x32_bf16(a, breg[0][3], acc[3], 0, 0, 0);
    }
    __syncthreads();   // all waves done reading buf 0 before Hs overlay

    // ---- epilogue: bias + ReLU -> Hs (bf16), overlays pool ----
    unsigned short (*Hs)[136] = (unsigned short (*)[136])pool;
    #pragma unroll
    for (int j = 0; j < 4; ++j) {
        int ncol = wc * 64 + j * 16 + r16;
        float bias = fc1_b[ncol];
        #pragma unroll
        for (int r = 0; r < 4; ++r) {
            int mrow = wr * 16 + kc * 4 + r;
            float h = acc[j][r] + bias;
            Hs[mrow][ncol] = f2bf(h > 0.f ? h : 0.f);
        }
    }
    __syncthreads();

    // ---- stage 2: out[64][10] = Hs @ fc2^T + b2 (fc2 bf16 from L1) ----
    #pragma unroll
    for (int it = 0; it < 2; ++it) {
        int idx = it * 512 + tid;              // 0..1023, valid < 640
        if (idx < BM * 10) {
            int row = idx / 10, j = idx - row * 10;
            if ((m0 + row) < B) {
                float sum = fc2_b[j];
                const unsigned short* wrow = fc2wb + j * 128;
                #pragma unroll
                for (int n8 = 0; n8 < 16; ++n8) {
                    short8 h = *reinterpret_cast<const short8*>(&Hs[row][n8 * 8]);
                    short8 w = *reinterpret_cast<const short8*>(wrow + n8 * 8);
                    #pragma unroll
                    for (int k2 = 0; k2 < 8; ++k2)
                        sum += bf2f(((unsigned short*)&h)[k2]) *
                               bf2f(((unsigned short*)&w)[k2]);
                }
                out[(size_t)(m0 + row) * 10 + j] = sum;
            }
        }
    }
}

extern "C" void kernel_launch(void* const* d_in, const int* in_sizes, int n_in,
                              void* d_out, int out_size, void* d_ws, size_t ws_size,
                              hipStream_t stream) {
    const float* x      = (const float*)d_in[0];
    const float* conv_w = (const float*)d_in[1];
    const float* fc1_w  = (const float*)d_in[2];
    const float* fc1_b  = (const float*)d_in[3];
    const float* fc2_w  = (const float*)d_in[4];
    const float* fc2_b  = (const float*)d_in[5];
    float* out = (float*)d_out;
    unsigned short* ws = (unsigned short*)d_ws;   // 103680 bf16 = 207360 B

    int B = in_sizes[0] / 784;

    weff_prep<<<(128 * 800 + 255) / 256, 256, 0, stream>>>(fc1_w, conv_w, fc2_w, ws);

    int nblk = (B + BM - 1) / BM;
    fused_fwd<<<nblk, 512, 0, stream>>>(x, ws, fc1_b, fc2_b, out, B);
}

// Round 15
// 58.463 us; speedup vs baseline: 1.4031x; 1.2813x over previous
//
#include <hip/hip_runtime.h>
#include <hip/hip_bf16.h>

typedef float  f32x4  __attribute__((ext_vector_type(4)));
typedef short  short8 __attribute__((ext_vector_type(8)));

#define NKT   25
#define BM    64
#define AB    4096            // A buf: [4][64][8] bf16
#define BB    8192            // B buf: [4][128][8] bf16
#define BOFFS (3 * AB)        // 12288
#define POOLB (3 * AB + 3 * BB)   // 36864 -> 4 blocks/CU

static __device__ __forceinline__ unsigned short f2bf(float f) {
    unsigned int u = __float_as_uint(f);
    unsigned int r = (u + 0x7fffu + ((u >> 16) & 1u)) >> 16;   // RNE
    return (unsigned short)r;
}
static __device__ __forceinline__ float bf2f(unsigned short h) {
    return __uint_as_float(((unsigned int)h) << 16);
}
static __device__ __forceinline__ uint2 pack4(f32x4 v) {
    __hip_bfloat162 p0 = __float22bfloat162_rn(make_float2(v[0], v[1]));
    __hip_bfloat162 p1 = __float22bfloat162_rn(make_float2(v[2], v[3]));
    uint2 r;
    r.x = *reinterpret_cast<unsigned int*>(&p0);
    r.y = *reinterpret_cast<unsigned int*>(&p1);
    return r;
}

// W_eff = fc1_w o ConvMatrix, layout [kt][k2][128 cols][8] bf16 at ws[0..102399];
// fc2 weights converted to bf16 at ws[102400..103679].
__global__ __launch_bounds__(256) void weff_prep(
    const float* __restrict__ fc1_w,    // [128][676]
    const float* __restrict__ conv_w,   // [3][3]
    const float* __restrict__ fc2_w,    // [10][128]
    unsigned short* __restrict__ ws)    // weff4 [25][4][128][8] ++ fc2wb [1280]
{
    int idx = blockIdx.x * 256 + threadIdx.x;   // o*800 + p
    if (idx >= 128 * 800) return;
    if (idx < 1280) ws[102400 + idx] = f2bf(fc2_w[idx]);
    int o = idx / 800, p = idx - o * 800;
    float s = 0.f;
    if (p < 784) {
        int y = p / 28, xx = p - y * 28;
        #pragma unroll
        for (int dr = 0; dr < 3; ++dr) {
            int r = y - dr;
            if (r < 0 || r > 25) continue;
            #pragma unroll
            for (int dc = 0; dc < 3; ++dc) {
                int c = xx - dc;
                if (c < 0 || c > 25) continue;
                s += fc1_w[o * 676 + r * 26 + c] * conv_w[dr * 3 + dc];
            }
        }
    }
    int kt = p >> 5, kk = p & 31;
    ws[kt * 4096 + (kk >> 3) * 1024 + o * 8 + (kk & 7)] = f2bf(s);
}

// Fused: H = relu(X @ Weff^T + b1); out = H @ fc2^T + b2
// BM=64, 36 KB LDS -> 4 blocks/CU = 32 waves/CU. Pipeline: GL_B issued
// BEFORE LD_A each step, av x4 register sets, uniform vmcnt(3) at each
// barrier => B flight 2 steps, A flight ~2.5 steps preserved across
// barriers. Best-measured configuration (58.95 us).
__global__ __launch_bounds__(512, 8) void fused_fwd(
    const float* __restrict__ x,              // [B][784]
    const unsigned short* __restrict__ weff4, // [25][4][128][8] bf16 (+fc2wb)
    const float* __restrict__ fc1_b,          // [128]
    const float* __restrict__ fc2_b,          // [10]
    float* __restrict__ out,                  // [B][10]
    int B)
{
    __shared__ __align__(16) char pool[POOLB];   // 36 KB; Hs overlays after

    const int tid  = threadIdx.x;
    const int lane = tid & 63;
    const int wid  = tid >> 6;                // 0..7
    const int wr   = wid >> 1;                // 0..3: 16-row band
    const int wc   = wid & 1;                 // 0..1: 64-col half
    const int r16  = lane & 15;
    const int kc   = lane >> 4;               // 0..3 (8-bf16 k-chunk)
    const int m0   = blockIdx.x * BM;
    const unsigned short* fc2wb = weff4 + 102400;

    // ---- A staging: thread t -> row sr, 4-f32 granule g
    const int sr = tid >> 3;                  // 0..63
    const int g  = tid & 7;
    int grow = m0 + sr; if (grow >= B) grow = B - 1;
    const float* xr = x + (size_t)grow * 784;
    const int awb = (g >> 1) * 1024 + sr * 16 + (g & 1) * 8;   // byte in A buf

    f32x4 av[4];

#define LD_A(s_, kt_) do {                                                    \
        int k_ = (kt_) * 32 + g * 4; if (k_ > 780) k_ = 0;                    \
        av[s_] = *reinterpret_cast<const f32x4*>(xr + k_);                    \
    } while (0)

#define WR_A(s_, bi_) do {                                                    \
        uint2 q_ = pack4(av[s_]);                                             \
        *reinterpret_cast<uint2*>(pool + (bi_) * AB + awb) = q_;              \
    } while (0)

#define GL_B(bi_, kt_) __builtin_amdgcn_global_load_lds(                      \
        (const __attribute__((address_space(1))) void*)                      \
            (weff4 + (size_t)(kt_) * 4096 + tid * 8),                         \
        (__attribute__((address_space(3))) void*)                            \
            (pool + BOFFS + (bi_) * BB + tid * 16), 16, 0, 0)

    // ---- frag read offsets (k-major, conflict-free dense 256B groups)
    const int aoff = kc * 1024 + (wr * 16 + r16) * 16;
    const int boff = BOFFS + kc * 2048 + (wc * 64 + r16) * 16;   // j: +256

    f32x4 acc[4];
    #pragma unroll
    for (int j = 0; j < 4; ++j) acc[j] = (f32x4)(0.f);

    asm volatile("s_waitcnt vmcnt(0)" ::: "memory");   // clean FIFO

    // ---- prologue: FIFO = [B0, B1, A0, A1, A2]; WR_A(0) drains A0 (+B0,B1)
    GL_B(0, 0); GL_B(1, 1);
    LD_A(0, 0); LD_A(1, 1); LD_A(2, 2);
    WR_A(0, 0);

    #pragma unroll
    for (int i = 0; i < NKT; ++i) {
        asm volatile("s_waitcnt vmcnt(3) lgkmcnt(0)" ::: "memory");
        __builtin_amdgcn_s_barrier();
        __builtin_amdgcn_sched_barrier(0);

        const char* pa = pool + (i % 3) * AB;
        const char* pb = pool + (i % 3) * BB;   // + BOFFS via boff
        short8 a0 = *reinterpret_cast<const short8*>(pa + aoff);
        short8 b0 = *reinterpret_cast<const short8*>(pb + boff);
        short8 b1 = *reinterpret_cast<const short8*>(pb + boff + 256);
        short8 b2 = *reinterpret_cast<const short8*>(pb + boff + 512);
        short8 b3 = *reinterpret_cast<const short8*>(pb + boff + 768);

        const int kb = (i + 2 <= 24) ? (i + 2) : 24;
        const int ka = (i + 3 <= 24) ? (i + 3) : 24;
        GL_B((i + 2) % 3, kb);                 // B before A (FIFO order)
        LD_A((i + 3) % 4, ka);
        WR_A((i + 1) % 4, (i + 1) % 3);

        acc[0] = __builtin_amdgcn_mfma_f32_16x16x32_bf16(a0, b0, acc[0], 0, 0, 0);
        acc[1] = __builtin_amdgcn_mfma_f32_16x16x32_bf16(a0, b1, acc[1], 0, 0, 0);
        acc[2] = __builtin_amdgcn_mfma_f32_16x16x32_bf16(a0, b2, acc[2], 0, 0, 0);
        acc[3] = __builtin_amdgcn_mfma_f32_16x16x32_bf16(a0, b3, acc[3], 0, 0, 0);
    }
#undef LD_A
#undef WR_A
#undef GL_B

    // drain dummy tail ops before overlaying the pool
    asm volatile("s_waitcnt vmcnt(0) lgkmcnt(0)" ::: "memory");
    __builtin_amdgcn_s_barrier();
    __builtin_amdgcn_sched_barrier(0);

    // ---- epilogue: bias + ReLU -> Hs (bf16), overlays pool ----
    unsigned short (*Hs)[136] = (unsigned short (*)[136])pool;
    #pragma unroll
    for (int j = 0; j < 4; ++j) {
        int ncol = wc * 64 + j * 16 + r16;
        float bias = fc1_b[ncol];
        #pragma unroll
        for (int r = 0; r < 4; ++r) {
            int mrow = wr * 16 + kc * 4 + r;
            float h = acc[j][r] + bias;
            Hs[mrow][ncol] = f2bf(h > 0.f ? h : 0.f);
        }
    }
    __syncthreads();

    // ---- stage 2: out[64][10] = Hs @ fc2^T + b2 (fc2 bf16 from L1) ----
    #pragma unroll
    for (int it = 0; it < 2; ++it) {
        int idx = it * 512 + tid;              // 0..1023, valid < 640
        if (idx < BM * 10) {
            int row = idx / 10, j = idx - row * 10;
            if ((m0 + row) < B) {
                float sum = fc2_b[j];
                const unsigned short* wrow = fc2wb + j * 128;
                #pragma unroll
                for (int n8 = 0; n8 < 16; ++n8) {
                    short8 h = *reinterpret_cast<const short8*>(&Hs[row][n8 * 8]);
                    short8 w = *reinterpret_cast<const short8*>(wrow + n8 * 8);
                    #pragma unroll
                    for (int k2 = 0; k2 < 8; ++k2)
                        sum += bf2f(((unsigned short*)&h)[k2]) *
                               bf2f(((unsigned short*)&w)[k2]);
                }
                out[(size_t)(m0 + row) * 10 + j] = sum;
            }
        }
    }
}

extern "C" void kernel_launch(void* const* d_in, const int* in_sizes, int n_in,
                              void* d_out, int out_size, void* d_ws, size_t ws_size,
                              hipStream_t stream) {
    const float* x      = (const float*)d_in[0];
    const float* conv_w = (const float*)d_in[1];
    const float* fc1_w  = (const float*)d_in[2];
    const float* fc1_b  = (const float*)d_in[3];
    const float* fc2_w  = (const float*)d_in[4];
    const float* fc2_b  = (const float*)d_in[5];
    float* out = (float*)d_out;
    unsigned short* ws = (unsigned short*)d_ws;   // 103680 bf16 = 207360 B

    int B = in_sizes[0] / 784;

    weff_prep<<<(128 * 800 + 255) / 256, 256, 0, stream>>>(fc1_w, conv_w, fc2_w, ws);

    int nblk = (B + BM - 1) / BM;
    fused_fwd<<<nblk, 512, 0, stream>>>(x, ws, fc1_b, fc2_b, out, B);
}